// Round 1
// baseline (73.547 us; speedup 1.0000x reference)
//
#include <hip/hip_runtime.h>

#define NBLK 128
#define BLK  8
#define BB   4
#define SS   4096
#define DD   1024
#define TOTAL (BB * SS * NBLK)     // 2,097,152 block-tasks
#define PLANE (BB * SS * DD)       // 16,777,216 floats per output plane

// ---------------------------------------------------------------------------
// Kernel 1: Cayley transform. 128 independent 16x16 solves (real-block
// isomorphism of the 8x8 complex system). 16 threads per solve, one row
// each; row kept in registers (32 floats, statically indexed after full
// unroll); pivot row broadcast through LDS. No pivoting: LHS = I + O(0.02).
// ---------------------------------------------------------------------------
__global__ __launch_bounds__(256) void cayley_kernel(
    const float* __restrict__ Ar, const float* __restrict__ Ai,
    float* __restrict__ Ur, float* __restrict__ Ui) {
  __shared__ float piv[16][33];          // +1 pad, mostly broadcast reads
  const int s = threadIdx.x >> 4;        // solve slot within workgroup
  const int r = threadIdx.x & 15;        // my row of the 16x32 augmented mat
  const int n = blockIdx.x * 16 + s;     // block index 0..127
  const float* arb = Ar + n * 64;
  const float* aib = Ai + n * 64;

  float row[32];                         // [LHS(16) | RHS(16)]
  if (r < 8) {
    #pragma unroll
    for (int c = 0; c < 8; ++c) {
      float sk = 0.5f * (arb[r * 8 + c] - arb[c * 8 + r]);  // A_r skew
      float sy = 0.5f * (aib[r * 8 + c] + aib[c * 8 + r]);  // A_i sym
      float d  = (c == r) ? 1.0f : 0.0f;
      row[c]      = d + sk;    // I + A_r
      row[8 + c]  = -sy;       // -A_i
      row[16 + c] = d - sk;    // I - A_r
      row[24 + c] = sy;        //  A_i
    }
  } else {
    const int rr = r - 8;
    #pragma unroll
    for (int c = 0; c < 8; ++c) {
      float sk = 0.5f * (arb[rr * 8 + c] - arb[c * 8 + rr]);
      float sy = 0.5f * (aib[rr * 8 + c] + aib[c * 8 + rr]);
      float d  = (c == rr) ? 1.0f : 0.0f;
      row[c]      = sy;        //  A_i
      row[8 + c]  = d + sk;    // I + A_r
      row[16 + c] = -sy;       // -A_i
      row[24 + c] = d - sk;    // I - A_r
    }
  }

  #pragma unroll
  for (int k = 0; k < 16; ++k) {
    if (r == k) {
      float inv = 1.0f / row[k];
      #pragma unroll
      for (int j = 0; j < 32; ++j) { row[j] *= inv; piv[s][j] = row[j]; }
    }
    __syncthreads();
    if (r != k) {
      float f = row[k];
      #pragma unroll
      for (int j = 0; j < 32; ++j) row[j] = fmaf(-f, piv[s][j], row[j]);
    }
    __syncthreads();
  }

  // Solution X sits in cols 16..31. U_real = X[0:8,0:8], U_imag = X[8:16,0:8].
  if (r < 8) {
    #pragma unroll
    for (int c = 0; c < 8; ++c) Ur[n * 64 + r * 8 + c] = row[16 + c];
  } else {
    #pragma unroll
    for (int c = 0; c < 8; ++c) Ui[n * 64 + (r - 8) * 8 + c] = row[16 + c];
  }
}

// ---------------------------------------------------------------------------
// Kernel 2: apply block-diagonal complex matmul. One thread per (b,s,n)
// 8-element block. Flat task index tau -> x offset tau*8 (fully coalesced
// float4 IO). Grid stride is a multiple of 128 so n = tid&127 is constant
// per thread: hoist U[n] (64+64 floats) into registers once, reuse over all
// tasks. No LDS. Memory-bound streaming kernel.
// ---------------------------------------------------------------------------
__global__ __launch_bounds__(256, 2) void apply_kernel(
    const float* __restrict__ xr, const float* __restrict__ xi,
    const float* __restrict__ Urg, const float* __restrict__ Uig,
    float* __restrict__ out) {
  const int n = threadIdx.x & 127;       // constant across grid-stride tasks

  float u[64], v[64];
  const float4* Ur4 = (const float4*)Urg + n * 16;
  const float4* Ui4 = (const float4*)Uig + n * 16;
  #pragma unroll
  for (int j = 0; j < 16; ++j) {
    float4 t = Ur4[j];
    u[4 * j] = t.x; u[4 * j + 1] = t.y; u[4 * j + 2] = t.z; u[4 * j + 3] = t.w;
    float4 w = Ui4[j];
    v[4 * j] = w.x; v[4 * j + 1] = w.y; v[4 * j + 2] = w.z; v[4 * j + 3] = w.w;
  }

  const int g = blockIdx.x * 256 + threadIdx.x;
  const int stride = gridDim.x * 256;    // 524288 = 0 mod 128
  for (int task = g; task < TOTAL; task += stride) {
    const float4* pxr = (const float4*)xr + task * 2;
    const float4* pxi = (const float4*)xi + task * 2;
    float4 a0 = pxr[0], a1 = pxr[1];
    float4 b0 = pxi[0], b1 = pxi[1];
    float xrv[8] = {a0.x, a0.y, a0.z, a0.w, a1.x, a1.y, a1.z, a1.w};
    float xiv[8] = {b0.x, b0.y, b0.z, b0.w, b1.x, b1.y, b1.z, b1.w};

    float orv[8], oiv[8];
    #pragma unroll
    for (int o = 0; o < 8; ++o) {
      float sr = 0.f, si = 0.f;
      #pragma unroll
      for (int i = 0; i < 8; ++i) {
        float ur = u[o * 8 + i], ui = v[o * 8 + i];
        sr = fmaf(ur, xrv[i], sr);
        sr = fmaf(-ui, xiv[i], sr);
        si = fmaf(ur, xiv[i], si);
        si = fmaf(ui, xrv[i], si);
      }
      orv[o] = sr; oiv[o] = si;
    }

    float4* por = (float4*)out + task * 2;
    float4* poi = (float4*)(out + PLANE) + task * 2;
    por[0] = make_float4(orv[0], orv[1], orv[2], orv[3]);
    por[1] = make_float4(orv[4], orv[5], orv[6], orv[7]);
    poi[0] = make_float4(oiv[0], oiv[1], oiv[2], oiv[3]);
    poi[1] = make_float4(oiv[4], oiv[5], oiv[6], oiv[7]);
  }
}

extern "C" void kernel_launch(void* const* d_in, const int* in_sizes, int n_in,
                              void* d_out, int out_size, void* d_ws, size_t ws_size,
                              hipStream_t stream) {
  const float* xr = (const float*)d_in[0];
  const float* xi = (const float*)d_in[1];
  const float* Ar = (const float*)d_in[2];
  const float* Ai = (const float*)d_in[3];
  float* out = (float*)d_out;

  float* Ur = (float*)d_ws;              // 128*64 floats = 32 KB
  float* Ui = Ur + NBLK * 64;            // next 32 KB

  cayley_kernel<<<8, 256, 0, stream>>>(Ar, Ai, Ur, Ui);
  apply_kernel<<<2048, 256, 0, stream>>>(xr, xi, Ur, Ui, out);
}

// Round 2
// 73.231 us; speedup vs baseline: 1.0043x; 1.0043x over previous
//
#include <hip/hip_runtime.h>

#define NBLK 128
#define BLK  8
#define BB   4
#define SS   4096
#define DD   1024
#define PLANE (BB * SS * DD)       // 16,777,216 floats per output plane
#define NTHREADS (2048 * 256)      // grid threads; PLANE/NTHREADS = 32 iters
#define NITER (PLANE / NTHREADS)   // 32

// ---------------------------------------------------------------------------
// Kernel 1: Cayley transform. 128 independent 16x16 solves (real-block
// isomorphism of the 8x8 complex system). 16 threads per solve, one row
// each; row kept in registers; pivot row broadcast through LDS.
// ---------------------------------------------------------------------------
__global__ __launch_bounds__(256) void cayley_kernel(
    const float* __restrict__ Ar, const float* __restrict__ Ai,
    float* __restrict__ Ur, float* __restrict__ Ui) {
  __shared__ float piv[16][33];
  const int s = threadIdx.x >> 4;
  const int r = threadIdx.x & 15;
  const int n = blockIdx.x * 16 + s;
  const float* arb = Ar + n * 64;
  const float* aib = Ai + n * 64;

  float row[32];
  if (r < 8) {
    #pragma unroll
    for (int c = 0; c < 8; ++c) {
      float sk = 0.5f * (arb[r * 8 + c] - arb[c * 8 + r]);
      float sy = 0.5f * (aib[r * 8 + c] + aib[c * 8 + r]);
      float d  = (c == r) ? 1.0f : 0.0f;
      row[c]      = d + sk;
      row[8 + c]  = -sy;
      row[16 + c] = d - sk;
      row[24 + c] = sy;
    }
  } else {
    const int rr = r - 8;
    #pragma unroll
    for (int c = 0; c < 8; ++c) {
      float sk = 0.5f * (arb[rr * 8 + c] - arb[c * 8 + rr]);
      float sy = 0.5f * (aib[rr * 8 + c] + aib[c * 8 + rr]);
      float d  = (c == rr) ? 1.0f : 0.0f;
      row[c]      = sy;
      row[8 + c]  = d + sk;
      row[16 + c] = -sy;
      row[24 + c] = d - sk;
    }
  }

  #pragma unroll
  for (int k = 0; k < 16; ++k) {
    if (r == k) {
      float inv = 1.0f / row[k];
      #pragma unroll
      for (int j = 0; j < 32; ++j) { row[j] *= inv; piv[s][j] = row[j]; }
    }
    __syncthreads();
    if (r != k) {
      float f = row[k];
      #pragma unroll
      for (int j = 0; j < 32; ++j) row[j] = fmaf(-f, piv[s][j], row[j]);
    }
    __syncthreads();
  }

  if (r < 8) {
    #pragma unroll
    for (int c = 0; c < 8; ++c) Ur[n * 64 + r * 8 + c] = row[16 + c];
  } else {
    #pragma unroll
    for (int c = 0; c < 8; ++c) Ui[n * 64 + (r - 8) * 8 + c] = row[16 + c];
  }
}

// ---------------------------------------------------------------------------
// Kernel 2: one OUTPUT ELEMENT per thread. Thread owns fixed (n, o):
//   n = (g & 1023) >> 3, o = g & 7  — constant across grid-stride (stride is
// a multiple of 1024). Per-thread U state = one row of Ur + one row of Ui
// (16 floats), pinned in VGPRs with an empty asm so the compiler cannot sink
// the loads into the loop (R1 failure mode: VGPR=88 proved U was re-read
// from L2 every task). The 8 lanes of each block-group issue IDENTICAL
// float4 loads for their block's x values -> in-wave broadcast coalescing.
// Stores are consecutive scalars -> perfectly coalesced.
// Per element: 4 float4 loads + 32 FMA + 2 stores. ~50 VGPR -> 8 waves/SIMD.
// ---------------------------------------------------------------------------
__global__ __launch_bounds__(256) void apply_kernel(
    const float* __restrict__ xr, const float* __restrict__ xi,
    const float* __restrict__ Urg, const float* __restrict__ Uig,
    float* __restrict__ out) {
  const int g = blockIdx.x * 256 + threadIdx.x;
  const int d = g & 1023;          // position in hidden dim, constant/thread
  const int n = d >> 3;            // block index
  const int o = d & 7;             // output row within block

  // Load my U row (Ur[n][o][:], Ui[n][o][:]) = 16 floats.
  float u[8], v[8];
  {
    const float4* ur4 = (const float4*)(Urg + n * 64 + o * 8);
    const float4* vi4 = (const float4*)(Uig + n * 64 + o * 8);
    float4 t0 = ur4[0], t1 = ur4[1], w0 = vi4[0], w1 = vi4[1];
    u[0] = t0.x; u[1] = t0.y; u[2] = t0.z; u[3] = t0.w;
    u[4] = t1.x; u[5] = t1.y; u[6] = t1.z; u[7] = t1.w;
    v[0] = w0.x; v[1] = w0.y; v[2] = w0.z; v[3] = w0.w;
    v[4] = w1.x; v[5] = w1.y; v[6] = w1.z; v[7] = w1.w;
  }
  // Pin in registers: forbid the compiler from sinking these loads into the
  // loop (each asm "modifies" the value, so a reload would be incorrect).
  #pragma unroll
  for (int j = 0; j < 8; ++j)
    asm volatile("" : "+v"(u[j]), "+v"(v[j]));

  // Walk 32 elements, stride NTHREADS (multiple of 1024).
  const float* pr = xr + (g & ~7);        // my block's x base
  const float* pi = xi + (g & ~7);
  float* qor = out + g;
  float* qoi = out + PLANE + g;

  #pragma unroll 2
  for (int it = 0; it < NITER; ++it) {
    float4 a0 = ((const float4*)pr)[0];
    float4 a1 = ((const float4*)pr)[1];
    float4 b0 = ((const float4*)pi)[0];
    float4 b1 = ((const float4*)pi)[1];

    float sr, si;
    sr = u[0] * a0.x;            si = u[0] * b0.x;
    sr = fmaf(u[1], a0.y, sr);   si = fmaf(u[1], b0.y, si);
    sr = fmaf(u[2], a0.z, sr);   si = fmaf(u[2], b0.z, si);
    sr = fmaf(u[3], a0.w, sr);   si = fmaf(u[3], b0.w, si);
    sr = fmaf(u[4], a1.x, sr);   si = fmaf(u[4], b1.x, si);
    sr = fmaf(u[5], a1.y, sr);   si = fmaf(u[5], b1.y, si);
    sr = fmaf(u[6], a1.z, sr);   si = fmaf(u[6], b1.z, si);
    sr = fmaf(u[7], a1.w, sr);   si = fmaf(u[7], b1.w, si);
    sr = fmaf(-v[0], b0.x, sr);  si = fmaf(v[0], a0.x, si);
    sr = fmaf(-v[1], b0.y, sr);  si = fmaf(v[1], a0.y, si);
    sr = fmaf(-v[2], b0.z, sr);  si = fmaf(v[2], a0.z, si);
    sr = fmaf(-v[3], b0.w, sr);  si = fmaf(v[3], a0.w, si);
    sr = fmaf(-v[4], b1.x, sr);  si = fmaf(v[4], a1.x, si);
    sr = fmaf(-v[5], b1.y, sr);  si = fmaf(v[5], a1.y, si);
    sr = fmaf(-v[6], b1.z, sr);  si = fmaf(v[6], a1.z, si);
    sr = fmaf(-v[7], b1.w, sr);  si = fmaf(v[7], a1.w, si);

    *qor = sr;
    *qoi = si;

    pr += NTHREADS; pi += NTHREADS; qor += NTHREADS; qoi += NTHREADS;
  }
}

extern "C" void kernel_launch(void* const* d_in, const int* in_sizes, int n_in,
                              void* d_out, int out_size, void* d_ws, size_t ws_size,
                              hipStream_t stream) {
  const float* xr = (const float*)d_in[0];
  const float* xi = (const float*)d_in[1];
  const float* Ar = (const float*)d_in[2];
  const float* Ai = (const float*)d_in[3];
  float* out = (float*)d_out;

  float* Ur = (float*)d_ws;              // 128*64 floats = 32 KB
  float* Ui = Ur + NBLK * 64;            // next 32 KB

  cayley_kernel<<<8, 256, 0, stream>>>(Ar, Ai, Ur, Ui);
  apply_kernel<<<2048, 256, 0, stream>>>(xr, xi, Ur, Ui, out);
}

// Round 3
// 61.242 us; speedup vs baseline: 1.2009x; 1.1958x over previous
//
#include <hip/hip_runtime.h>

#define NBLK 128
#define BLK  8
#define BB   4
#define SS   4096
#define DD   1024
#define PLANE (BB * SS * DD)         // 16,777,216 floats per output plane
#define APPLY_WGS 16384
#define NTHREADS (APPLY_WGS * 256)   // 4,194,304 threads
#define NITER (PLANE / NTHREADS)     // 4 iterations per thread

// ---------------------------------------------------------------------------
// Kernel 1: Cayley transform. 128 independent 16x16 solves (real-block
// isomorphism of the 8x8 complex system). 16 threads per solve, one row
// each; row kept in registers; pivot row broadcast through LDS.
// ---------------------------------------------------------------------------
__global__ __launch_bounds__(256) void cayley_kernel(
    const float* __restrict__ Ar, const float* __restrict__ Ai,
    float* __restrict__ Ur, float* __restrict__ Ui) {
  __shared__ float piv[16][33];
  const int s = threadIdx.x >> 4;
  const int r = threadIdx.x & 15;
  const int n = blockIdx.x * 16 + s;
  const float* arb = Ar + n * 64;
  const float* aib = Ai + n * 64;

  float row[32];
  if (r < 8) {
    #pragma unroll
    for (int c = 0; c < 8; ++c) {
      float sk = 0.5f * (arb[r * 8 + c] - arb[c * 8 + r]);
      float sy = 0.5f * (aib[r * 8 + c] + aib[c * 8 + r]);
      float d  = (c == r) ? 1.0f : 0.0f;
      row[c]      = d + sk;
      row[8 + c]  = -sy;
      row[16 + c] = d - sk;
      row[24 + c] = sy;
    }
  } else {
    const int rr = r - 8;
    #pragma unroll
    for (int c = 0; c < 8; ++c) {
      float sk = 0.5f * (arb[rr * 8 + c] - arb[c * 8 + rr]);
      float sy = 0.5f * (aib[rr * 8 + c] + aib[c * 8 + rr]);
      float d  = (c == rr) ? 1.0f : 0.0f;
      row[c]      = sy;
      row[8 + c]  = d + sk;
      row[16 + c] = -sy;
      row[24 + c] = d - sk;
    }
  }

  #pragma unroll
  for (int k = 0; k < 16; ++k) {
    if (r == k) {
      float inv = 1.0f / row[k];
      #pragma unroll
      for (int j = 0; j < 32; ++j) { row[j] *= inv; piv[s][j] = row[j]; }
    }
    __syncthreads();
    if (r != k) {
      float f = row[k];
      #pragma unroll
      for (int j = 0; j < 32; ++j) row[j] = fmaf(-f, piv[s][j], row[j]);
    }
    __syncthreads();
  }

  if (r < 8) {
    #pragma unroll
    for (int c = 0; c < 8; ++c) Ur[n * 64 + r * 8 + c] = row[16 + c];
  } else {
    #pragma unroll
    for (int c = 0; c < 8; ++c) Ui[n * 64 + (r - 8) * 8 + c] = row[16 + c];
  }
}

// ---------------------------------------------------------------------------
// Kernel 2: one output element per thread; (n,o) fixed per thread (stride is
// a multiple of 1024). U row (16 floats) pinned in VGPRs. 16384 wgs x 4
// iterations: short serial chains, many independent waves.
// NON-TEMPORAL stores: out is never re-read; bypassing L3 keeps all 128 MB
// of x resident in L3 across graph replays (R2 counters showed out-writes
// evicting half of x: FETCH=66MB). Expect FETCH -> ~0, HBM traffic ~134MB.
// ---------------------------------------------------------------------------
__global__ __launch_bounds__(256) void apply_kernel(
    const float* __restrict__ xr, const float* __restrict__ xi,
    const float* __restrict__ Urg, const float* __restrict__ Uig,
    float* __restrict__ out) {
  const int g = blockIdx.x * 256 + threadIdx.x;
  const int d = g & 1023;          // position in hidden dim, constant/thread
  const int n = d >> 3;            // block index
  const int o = d & 7;             // output row within block

  // Load my U row (Ur[n][o][:], Ui[n][o][:]) = 16 floats, pin in VGPRs.
  float u[8], v[8];
  {
    const float4* ur4 = (const float4*)(Urg + n * 64 + o * 8);
    const float4* vi4 = (const float4*)(Uig + n * 64 + o * 8);
    float4 t0 = ur4[0], t1 = ur4[1], w0 = vi4[0], w1 = vi4[1];
    u[0] = t0.x; u[1] = t0.y; u[2] = t0.z; u[3] = t0.w;
    u[4] = t1.x; u[5] = t1.y; u[6] = t1.z; u[7] = t1.w;
    v[0] = w0.x; v[1] = w0.y; v[2] = w0.z; v[3] = w0.w;
    v[4] = w1.x; v[5] = w1.y; v[6] = w1.z; v[7] = w1.w;
  }
  #pragma unroll
  for (int j = 0; j < 8; ++j)
    asm volatile("" : "+v"(u[j]), "+v"(v[j]));

  const float* pr = xr + (g & ~7);
  const float* pi = xi + (g & ~7);
  float* qor = out + g;
  float* qoi = out + PLANE + g;

  #pragma unroll 2
  for (int it = 0; it < NITER; ++it) {
    float4 a0 = ((const float4*)pr)[0];
    float4 a1 = ((const float4*)pr)[1];
    float4 b0 = ((const float4*)pi)[0];
    float4 b1 = ((const float4*)pi)[1];

    float sr, si;
    sr = u[0] * a0.x;            si = u[0] * b0.x;
    sr = fmaf(u[1], a0.y, sr);   si = fmaf(u[1], b0.y, si);
    sr = fmaf(u[2], a0.z, sr);   si = fmaf(u[2], b0.z, si);
    sr = fmaf(u[3], a0.w, sr);   si = fmaf(u[3], b0.w, si);
    sr = fmaf(u[4], a1.x, sr);   si = fmaf(u[4], b1.x, si);
    sr = fmaf(u[5], a1.y, sr);   si = fmaf(u[5], b1.y, si);
    sr = fmaf(u[6], a1.z, sr);   si = fmaf(u[6], b1.z, si);
    sr = fmaf(u[7], a1.w, sr);   si = fmaf(u[7], b1.w, si);
    sr = fmaf(-v[0], b0.x, sr);  si = fmaf(v[0], a0.x, si);
    sr = fmaf(-v[1], b0.y, sr);  si = fmaf(v[1], a0.y, si);
    sr = fmaf(-v[2], b0.z, sr);  si = fmaf(v[2], a0.z, si);
    sr = fmaf(-v[3], b0.w, sr);  si = fmaf(v[3], a0.w, si);
    sr = fmaf(-v[4], b1.x, sr);  si = fmaf(v[4], a1.x, si);
    sr = fmaf(-v[5], b1.y, sr);  si = fmaf(v[5], a1.y, si);
    sr = fmaf(-v[6], b1.z, sr);  si = fmaf(v[6], a1.z, si);
    sr = fmaf(-v[7], b1.w, sr);  si = fmaf(v[7], a1.w, si);

    __builtin_nontemporal_store(sr, qor);
    __builtin_nontemporal_store(si, qoi);

    pr += NTHREADS; pi += NTHREADS; qor += NTHREADS; qoi += NTHREADS;
  }
}

extern "C" void kernel_launch(void* const* d_in, const int* in_sizes, int n_in,
                              void* d_out, int out_size, void* d_ws, size_t ws_size,
                              hipStream_t stream) {
  const float* xr = (const float*)d_in[0];
  const float* xi = (const float*)d_in[1];
  const float* Ar = (const float*)d_in[2];
  const float* Ai = (const float*)d_in[3];
  float* out = (float*)d_out;

  float* Ur = (float*)d_ws;              // 128*64 floats = 32 KB
  float* Ui = Ur + NBLK * 64;            // next 32 KB

  cayley_kernel<<<8, 256, 0, stream>>>(Ar, Ai, Ur, Ui);
  apply_kernel<<<APPLY_WGS, 256, 0, stream>>>(xr, xi, Ur, Ui, out);
}